// Round 8
// baseline (358.395 us; speedup 1.0000x reference)
//
#include <hip/hip_runtime.h>

// PointTransformerLayer fused kernel (MI355X / gfx950) — round 8
//
// Math (verified: bf16 path R2/R4 absmax 0.031; qk-factorization R5 passed):
//   relu1 = relu(aI_i - a_j)                 aI = pos@pW1+pb1, a = pos@pW1
//   S1    = relu1 @ W_pa + cq_i[t] - ka_j[t]   W_pa = pW2@aW1 (K=64 MFMA)
//           cq = ab1 + pb2@aW1 + q@aW1, ka = k@aW1 (both f32, prep)
//   H     = relu(S1)
//   simL2 = H @ (aW2*log2e)                  (ab2 softmax-invariant)
//   rpe   = relu1 @ pW2 ; vv = (v+pb2)_j + rpe   (v folded into G3 C-op)
//   out_i[d] = sum_j 2^simL2 * vv / sum_j 2^simL2
//
// R8 = R4 skeleton (j-tile 32, 1 barrier/iter, w-ownership for G2/G3) with:
//   - G1 K=64: qk term computed in f32 at prep (R5-verified), ka enters as
//     the MFMA C-OPERAND (C = cq_splat + ka, added by the matrix unit) —
//     fixes R5's post-MFMA v_adds; matrix work -31%, Bf 16->8 frags.
//   - builders: waves 0,1 only (relu1 halves); AfL 16KB->8KB.
//   - register diet (est ~155 peak) + LDS 42KB + __launch_bounds__(256,3)
//     -> target 3 blocks/CU (R4 stalls ~50% at 2 waves/SIMD; R6/R7 showed
//     +24 regs = +11us, so occupancy is the binding resource).

typedef float f32x4 __attribute__((ext_vector_type(4)));
using sh8 = __attribute__((ext_vector_type(8))) short;  // 8 bf16 (4 VGPRs)

static constexpr int NPTS = 1024;

// ---- ws layout (bytes) — R5's (verified) ----
static constexpr size_t BEXT_OFF = 0;        // W_pa frags: 2*16*64*8 bf16 = 32768
static constexpr size_t AW2F_OFF = 32768;    // aW2*log2e frags: 32768
static constexpr size_t PW2F_OFF = 65536;    // pW2 frags: 8192
static constexpr size_t AI_OFF   = 73728;    // 1024*64 f32 (+pb1)
static constexpr size_t AJ_OFF   = 335872;   // 1024*64 bf16
static constexpr size_t VPT_OFF  = 466944;   // 64*1024 f32 (v+pb2 transposed)
static constexpr size_t CQ_OFF   = 729088;   // 1024*256 f32: ab1 + pb2@aW1 + q@aW1
static constexpr size_t KAT_OFF  = 1777664;  // 256*1024 f32: -(k@aW1) transposed

__device__ __forceinline__ unsigned short f2b_rne(float f) {
    unsigned u = __float_as_uint(f);
    u += 0x7fffu + ((u >> 16) & 1u);
    return (unsigned short)(u >> 16);
}
// trunc-pack two f32 into bf16x2 — single v_perm_b32
__device__ __forceinline__ unsigned pk2(float lo, float hi) {
    return __builtin_amdgcn_perm(__float_as_uint(hi), __float_as_uint(lo), 0x07060302);
}
__device__ __forceinline__ float b2f(unsigned short s) {
    return __uint_as_float(((unsigned)s) << 16);
}

// ---------------- combined prep: weights (blocks 0..143) + points (144..399) ----------------
// (R5's prep, verified correct end-to-end)
__global__ void prep_all(const float* __restrict__ x, const float* __restrict__ pos,
                         const float* __restrict__ Wq, const float* __restrict__ Wk,
                         const float* __restrict__ Wv, const float* __restrict__ pW1,
                         const float* __restrict__ pb1, const float* __restrict__ pW2,
                         const float* __restrict__ pb2, const float* __restrict__ aW1,
                         const float* __restrict__ ab1, const float* __restrict__ aW2,
                         unsigned short* __restrict__ bextf, unsigned short* __restrict__ aw2f,
                         unsigned short* __restrict__ pw2f,
                         float* __restrict__ aI, unsigned short* __restrict__ aJ,
                         float* __restrict__ vPT, float* __restrict__ cq,
                         float* __restrict__ kaT)
{
    const int b = blockIdx.x;
    if (b < 144) {
        const int idx = b * 256 + threadIdx.x;
        if (idx < 16384) {
            // W_pa[k][t] = pW2@aW1, k<64 -> B-frag layout (R2-verified)
            const int k = idx >> 8, t = idx & 255;
            float s = 0.f;
            for (int d = 0; d < 64; ++d) s = fmaf(pW2[k * 64 + d], aW1[d * 256 + t], s);
            const int kc = k >> 5, kl = k & 31, qq = kl >> 3, e = kl & 7;
            const int ntg = t >> 4, tl = t & 15;
            bextf[(((size_t)(kc * 16 + ntg) * 64) + (qq * 16 + tl)) * 8 + e] = f2b_rne(s);
        } else if (idx < 32768) {
            // aW2*log2e frags, permuted K matching H LDS layout (R2-verified)
            const int r = idx - 16384;
            const int kp = r >> 6, d = r & 63;
            const int t = 64 * (kp >> 6) + 16 * (kp & 3) + ((kp >> 2) & 15);  // inverse perm
            const int kc = kp >> 5, kl = kp & 31, qq = kl >> 3, e = kl & 7;
            const int nt = d >> 4, dl = d & 15;
            aw2f[(((size_t)(kc * 4 + nt) * 64) + (qq * 16 + dl)) * 8 + e] =
                f2b_rne(aW2[t * 64 + d] * 1.4426950408889634f);
        } else if (idx < 36864) {
            // pW2 frags (R2-verified)
            const int r = idx - 32768;
            const int k = r >> 6, d = r & 63;
            const int kc = k >> 5, kl = k & 31, qq = kl >> 3, e = kl & 7;
            const int nt = d >> 4, dl = d & 15;
            pw2f[(((size_t)(kc * 4 + nt) * 64) + (qq * 16 + dl)) * 8 + e] = f2b_rne(pW2[k * 64 + d]);
        }
    } else {
        // per-point prep: 4 points per block
        const int tid = threadIdx.x, sub = tid >> 6, d = tid & 63;
        const int i0 = (b - 144) * 4;
        __shared__ float xs[4][64], qs[4][64], ks[4][64];
        xs[sub][d] = x[(i0 + sub) * 64 + d];
        __syncthreads();
        float q = 0.f, k = 0.f, v = 0.f;
        for (int e = 0; e < 64; ++e) {
            const float xe = xs[sub][e];
            q = fmaf(xe, Wq[e * 64 + d], q);
            k = fmaf(xe, Wk[e * 64 + d], k);
            v = fmaf(xe, Wv[e * 64 + d], v);
        }
        const float a = pos[(i0 + sub) * 2] * pW1[d] + pos[(i0 + sub) * 2 + 1] * pW1[64 + d];
        qs[sub][d] = q;
        ks[sub][d] = k;
        vPT[d * NPTS + i0 + sub] = v + pb2[d];
        aI[(i0 + sub) * 64 + d] = a + pb1[d];
        aJ[(i0 + sub) * 64 + d] = f2b_rne(a);
        __syncthreads();
        // phase B: thread t computes c[t], qa[i][t], ka[i][t] for the 4 points (f32)
        const int t = tid;
        float c = ab1[t];
        float qa0 = 0.f, qa1 = 0.f, qa2 = 0.f, qa3 = 0.f;
        float ka0 = 0.f, ka1 = 0.f, ka2 = 0.f, ka3 = 0.f;
        for (int dd = 0; dd < 64; ++dd) {
            const float wv = aW1[dd * 256 + t];
            c   = fmaf(pb2[dd],   wv, c);
            qa0 = fmaf(qs[0][dd], wv, qa0);
            qa1 = fmaf(qs[1][dd], wv, qa1);
            qa2 = fmaf(qs[2][dd], wv, qa2);
            qa3 = fmaf(qs[3][dd], wv, qa3);
            ka0 = fmaf(ks[0][dd], wv, ka0);
            ka1 = fmaf(ks[1][dd], wv, ka1);
            ka2 = fmaf(ks[2][dd], wv, ka2);
            ka3 = fmaf(ks[3][dd], wv, ka3);
        }
        cq[(i0 + 0) * 256 + t] = c + qa0;
        cq[(i0 + 1) * 256 + t] = c + qa1;
        cq[(i0 + 2) * 256 + t] = c + qa2;
        cq[(i0 + 3) * 256 + t] = c + qa3;
        float4 kn;
        kn.x = -ka0; kn.y = -ka1; kn.z = -ka2; kn.w = -ka3;
        *(float4*)(kaT + (size_t)t * NPTS + i0) = kn;
    }
}

// ---------------- main fused kernel: one block per query i, j-tile 32 ----------------
__global__ __launch_bounds__(256, 3) void ptl_main(
    const float* __restrict__ aI, const unsigned short* __restrict__ aJ,
    const float* __restrict__ vPT, const float* __restrict__ cq,
    const float* __restrict__ kaT,
    const unsigned short* __restrict__ bextf, const unsigned short* __restrict__ aw2f,
    const unsigned short* __restrict__ pw2f, float* __restrict__ out)
{
    const int i    = blockIdx.x;
    const int tid  = threadIdx.x;
    const int w    = tid >> 6;    // wave: t-slice [64w,64w+64) for G1, d-slice [16w,16w+16) for G2/G3
    const int lane = tid & 63;
    const int m    = lane & 15;
    const int q    = lane >> 4;

    // double-buffered LDS: [buf][sub]  (8 KB + 33 KB = 41 KB -> 3 blocks/CU)
    __shared__ __align__(16) uint4 AfL[2][2][2][64];               // [buf][sub][kchalf][lane]
    __shared__ __align__(16) unsigned char Hs[2][2][16 * 528];

    // constant B fragments (R8 diet: 8+8+2 = 18 frags = 72 regs)
    sh8 Bf[8];   // G1 W_pa: [kc 0..1][nt 0..3], t-slice 64w
#pragma unroll
    for (int kc = 0; kc < 2; ++kc)
#pragma unroll
        for (int nt = 0; nt < 4; ++nt)
            Bf[kc * 4 + nt] = *(const sh8*)(bextf + ((size_t)((kc * 16 + 4 * w + nt) * 64 + lane)) * 8);
    sh8 W2f[8];  // G2: [kc 0..7], d-slice w
#pragma unroll
    for (int kc = 0; kc < 8; ++kc)
        W2f[kc] = *(const sh8*)(aw2f + ((size_t)((kc * 4 + w) * 64 + lane)) * 8);
    sh8 P2f[2];  // G3: [kc 0..1], d-slice w
#pragma unroll
    for (int kc = 0; kc < 2; ++kc)
        P2f[kc] = *(const sh8*)(pw2f + ((size_t)((kc * 4 + w) * 64 + lane)) * 8);

    // cq (bias + q@aW1) splat per G1 output column t = 64w+16nt+m
    float creg[4];
#pragma unroll
    for (int nt = 0; nt < 4; ++nt) creg[nt] = cq[i * 256 + 64 * w + 16 * nt + m];

    // builder: waves 0,1 build relu1 k-half w for both subs
    const unsigned short* bsrc  = aJ + m * 64 + w * 32 + q * 8;   // valid only w<2
    float iv[8];
    if (w < 2) {
        const float* ibase = aI + i * 64 + w * 32 + q * 8;
        *(float4*)(iv)     = *(const float4*)(ibase);
        *(float4*)(iv + 4) = *(const float4*)(ibase + 4);
        // prologue: build both subs of tile 0 into buffer 0
#pragma unroll
        for (int s = 0; s < 2; ++s) {
            const sh8 raw = *(const sh8*)(bsrc + (size_t)(16 * s) * 64);
            float t[8];
#pragma unroll
            for (int e = 0; e < 8; ++e) t[e] = fmaxf(iv[e] - b2f((unsigned short)raw[e]), 0.f);
            uint4 pk;
            pk.x = pk2(t[0], t[1]); pk.y = pk2(t[2], t[3]);
            pk.z = pk2(t[4], t[5]); pk.w = pk2(t[6], t[7]);
            AfL[0][s][w][lane] = pk;
        }
    }
    __syncthreads();

    float num = 0.f, den = 0.f;
    const f32x4 z4 = {0.f, 0.f, 0.f, 0.f};
    const float* vbase = vPT + (size_t)(16 * w + m) * NPTS;
    const float* kab   = kaT + (size_t)(64 * w + m) * NPTS + 4 * q;  // + 16nt*NPTS + j

    for (int n = 0; n < 32; ++n) {
        const int pb = n & 1, nb = pb ^ 1;
        const int j0 = n << 5;

        // next tile's raw global loads (builder waves), issued early
        sh8 raw0, raw1;
        if (w < 2 && n < 31) {
            raw0 = *(const sh8*)(bsrc + (size_t)(j0 + 32) * 64);
            raw1 = *(const sh8*)(bsrc + (size_t)(j0 + 48) * 64);
        }
        // v values (G3 C-op) and ka values (G1 C-op), issued before the MFMA chain
        const float4 vj0 = *(const float4*)(vbase + j0 + 4 * q);
        const float4 vj1 = *(const float4*)(vbase + j0 + 16 + 4 * q);
        f32x4 ka0[4], ka1[4];
#pragma unroll
        for (int nt = 0; nt < 4; ++nt) {
            ka0[nt] = *(const f32x4*)(kab + (size_t)(16 * nt) * NPTS + j0);
            ka1[nt] = *(const f32x4*)(kab + (size_t)(16 * nt) * NPTS + j0 + 16);
        }

        // A fragments (relu1) — live through G3
        const sh8 A00 = *(const sh8*)&AfL[pb][0][0][lane];
        const sh8 A01 = *(const sh8*)&AfL[pb][0][1][lane];
        const sh8 A10 = *(const sh8*)&AfL[pb][1][0][lane];
        const sh8 A11 = *(const sh8*)&AfL[pb][1][1][lane];

        // ---- G1 sub0 (K=64): C-operand = cq + ka ----
        {
            f32x4 acc[4];
#pragma unroll
            for (int nt = 0; nt < 4; ++nt) {
                f32x4 cv = ka0[nt];
#pragma unroll
                for (int r = 0; r < 4; ++r) cv[r] += creg[nt];
                acc[nt] = __builtin_amdgcn_mfma_f32_16x16x32_bf16(A00, Bf[nt], cv, 0, 0, 0);
                acc[nt] = __builtin_amdgcn_mfma_f32_16x16x32_bf16(A01, Bf[4 + nt], acc[nt], 0, 0, 0);
            }
            unsigned char* hw = Hs[pb][0] + (4 * q) * 528 + 128 * w + 8 * m;
#pragma unroll
            for (int r = 0; r < 4; ++r) {
                uint2 pk;
                pk.x = pk2(fmaxf(acc[0][r], 0.f), fmaxf(acc[1][r], 0.f));
                pk.y = pk2(fmaxf(acc[2][r], 0.f), fmaxf(acc[3][r], 0.f));
                *(uint2*)(hw + r * 528) = pk;
            }
        }
        // ---- G1 sub1 ----
        {
            f32x4 acc[4];
#pragma unroll
            for (int nt = 0; nt < 4; ++nt) {
                f32x4 cv = ka1[nt];
#pragma unroll
                for (int r = 0; r < 4; ++r) cv[r] += creg[nt];
                acc[nt] = __builtin_amdgcn_mfma_f32_16x16x32_bf16(A10, Bf[nt], cv, 0, 0, 0);
                acc[nt] = __builtin_amdgcn_mfma_f32_16x16x32_bf16(A11, Bf[4 + nt], acc[nt], 0, 0, 0);
            }
            unsigned char* hw = Hs[pb][1] + (4 * q) * 528 + 128 * w + 8 * m;
#pragma unroll
            for (int r = 0; r < 4; ++r) {
                uint2 pk;
                pk.x = pk2(fmaxf(acc[0][r], 0.f), fmaxf(acc[1][r], 0.f));
                pk.y = pk2(fmaxf(acc[2][r], 0.f), fmaxf(acc[3][r], 0.f));
                *(uint2*)(hw + r * 528) = pk;
            }
        }

        // build next tile's relu1 A-frags (waves 0,1)
        if (w < 2 && n < 31) {
#pragma unroll
            for (int s = 0; s < 2; ++s) {
                const sh8 raw = s ? raw1 : raw0;
                float t[8];
#pragma unroll
                for (int e = 0; e < 8; ++e) t[e] = fmaxf(iv[e] - b2f((unsigned short)raw[e]), 0.f);
                uint4 pk;
                pk.x = pk2(t[0], t[1]); pk.y = pk2(t[2], t[3]);
                pk.z = pk2(t[4], t[5]); pk.w = pk2(t[6], t[7]);
                AfL[nb][s][w][lane] = pk;
            }
        }

        __syncthreads();  // the ONE barrier per 32 j

        // ---- G2: simL2 for d-slice w (R4 ownership) ----
        f32x4 aS0 = z4, aS1 = z4;
#pragma unroll
        for (int kc = 0; kc < 8; ++kc) {
            const sh8 hf0 = *(const sh8*)(Hs[pb][0] + m * 528 + kc * 64 + 16 * q);
            aS0 = __builtin_amdgcn_mfma_f32_16x16x32_bf16(hf0, W2f[kc], aS0, 0, 0, 0);
            const sh8 hf1 = *(const sh8*)(Hs[pb][1] + m * 528 + kc * 64 + 16 * q);
            aS1 = __builtin_amdgcn_mfma_f32_16x16x32_bf16(hf1, W2f[kc], aS1, 0, 0, 0);
        }
        // ---- G3: rpe + v (C-op) ----
        const f32x4 vc0 = {vj0.x, vj0.y, vj0.z, vj0.w};
        const f32x4 vc1 = {vj1.x, vj1.y, vj1.z, vj1.w};
        f32x4 aR0 = __builtin_amdgcn_mfma_f32_16x16x32_bf16(A00, P2f[0], vc0, 0, 0, 0);
        aR0 = __builtin_amdgcn_mfma_f32_16x16x32_bf16(A01, P2f[1], aR0, 0, 0, 0);
        f32x4 aR1 = __builtin_amdgcn_mfma_f32_16x16x32_bf16(A10, P2f[0], vc1, 0, 0, 0);
        aR1 = __builtin_amdgcn_mfma_f32_16x16x32_bf16(A11, P2f[1], aR1, 0, 0, 0);

        // online accumulation
#pragma unroll
        for (int r = 0; r < 4; ++r) {
            const float e0 = exp2f(aS0[r]);
            num = fmaf(e0, aR0[r], num);
            den += e0;
            const float e1 = exp2f(aS1[r]);
            num = fmaf(e1, aR1[r], num);
            den += e1;
        }
    }

    // reduce the 4 quad-partials (lanes m, m+16, m+32, m+48)
    num += __shfl_xor(num, 16);
    num += __shfl_xor(num, 32);
    den += __shfl_xor(den, 16);
    den += __shfl_xor(den, 32);
    if (q == 0) out[i * 64 + 16 * w + m] = num / den;
}

extern "C" void kernel_launch(void* const* d_in, const int* in_sizes, int n_in,
                              void* d_out, int out_size, void* d_ws, size_t ws_size,
                              hipStream_t stream) {
    const float* x   = (const float*)d_in[0];
    const float* pos = (const float*)d_in[1];
    const float* Wq  = (const float*)d_in[2];
    const float* Wk  = (const float*)d_in[3];
    const float* Wv  = (const float*)d_in[4];
    const float* pW1 = (const float*)d_in[5];
    const float* pb1 = (const float*)d_in[6];
    const float* pW2 = (const float*)d_in[7];
    const float* pb2 = (const float*)d_in[8];
    const float* aW1 = (const float*)d_in[9];
    const float* ab1 = (const float*)d_in[10];
    const float* aW2 = (const float*)d_in[11];
    // d_in[12] = ab2: constant over j -> cancels in per-channel softmax, unused.

    char* ws = (char*)d_ws;
    unsigned short* bextf = (unsigned short*)(ws + BEXT_OFF);
    unsigned short* aw2f  = (unsigned short*)(ws + AW2F_OFF);
    unsigned short* pw2f  = (unsigned short*)(ws + PW2F_OFF);
    float*          aIa   = (float*)(ws + AI_OFF);
    unsigned short* aJa   = (unsigned short*)(ws + AJ_OFF);
    float*          vPTa  = (float*)(ws + VPT_OFF);
    float*          cqa   = (float*)(ws + CQ_OFF);
    float*          kaTa  = (float*)(ws + KAT_OFF);

    prep_all<<<400, 256, 0, stream>>>(x, pos, Wq, Wk, Wv, pW1, pb1, pW2, pb2, aW1, ab1, aW2,
                                      bextf, aw2f, pw2f, aIa, aJa, vPTa, cqa, kaTa);
    ptl_main<<<NPTS, 256, 0, stream>>>(aIa, aJa, vPTa, cqa, kaTa, bextf, aw2f, pw2f,
                                       (float*)d_out);
}

// Round 9
// 189.714 us; speedup vs baseline: 1.8891x; 1.8891x over previous
//
#include <hip/hip_runtime.h>

// PointTransformerLayer fused kernel (MI355X / gfx950) — round 9
//
// Math (bf16 path verified R2/R4 absmax 0.031):
//   relu1 = relu(aI_i - a_j)            aI = pos@pW1 + pb1, a = pos@pW1
//   S1    = [relu1 | (q_i - k_j)] @ [[W_pa],[aW1]]   (K=128), W_pa = pW2@aW1
//   H     = relu(S1 + c), c = ab1 + pb2@aW1          (c folded into G1 C-op)
//   simL2 = H @ (aW2*log2e)              (ab2 softmax-invariant -> dropped)
//   rpe   = relu1 @ pW2 ; vv = (v+pb2)_j + rpe       (v folded into G3 C-op)
//   out_i[d] = sum_j 2^simL2 * vv / sum_j 2^simL2
//
// R9 = R4 (133us anchor) + fp8 H/G2 ONLY (R3 decomposition: G1-input fp8 was
// the error killer; G2-only adds ~0.05-0.08 RSS -> predicted 0.06-0.09 vs
// threshold 0.114). H stored e4m3 (Hs 33->17 KB, stride 272B), G2 via
// mfma_scale_f32_16x16x128_f8f6f4 (4 instr/iter vs 16), W2f 32->16 regs.
// G1/G3/builders unchanged. launch_bounds(256,2) — R8 proved bounds=3 spills
// (17.7MB scratch WRITE_SIZE); R6/R7 proved +24 regs = +11us, this is -16.

typedef float f32x4 __attribute__((ext_vector_type(4)));
typedef int   i32x8 __attribute__((ext_vector_type(8)));
using sh8 = __attribute__((ext_vector_type(8))) short;  // 8 bf16 (4 VGPRs)

static constexpr int NPTS = 1024;

// ---- ws layout (bytes) — same regions as R4 (aw2f now fp8, uses half) ----
static constexpr size_t BEXT_OFF = 0;        // 4*16*64*8 bf16  = 65536 B
static constexpr size_t AW2F_OFF = 65536;    // fp8 frags: 2*4*64*32 = 16384 B
static constexpr size_t PW2F_OFF = 98304;    // 2*4*64*8 bf16   = 8192 B
static constexpr size_t CARR_OFF = 106496;   // 256 f32         = 1024 B
static constexpr size_t AI_OFF   = 107520;   // 1024*64 f32 (+pb1)
static constexpr size_t QI_OFF   = 369664;   // 1024*64 f32
static constexpr size_t VPT_OFF  = 631808;   // 64*1024 f32 (v+pb2, transposed)
static constexpr size_t AJ_OFF   = 893952;   // 1024*64 bf16
static constexpr size_t KN_OFF   = 1025024;  // 1024*64 bf16 (negated k)

__device__ __forceinline__ unsigned short f2b_rne(float f) {
    unsigned u = __float_as_uint(f);
    u += 0x7fffu + ((u >> 16) & 1u);
    return (unsigned short)(u >> 16);
}
// trunc-pack two f32 into bf16x2 — single v_perm_b32
__device__ __forceinline__ unsigned pk2(float lo, float hi) {
    return __builtin_amdgcn_perm(__float_as_uint(hi), __float_as_uint(lo), 0x07060302);
}
__device__ __forceinline__ float b2f(unsigned short s) {
    return __uint_as_float(((unsigned)s) << 16);
}
__device__ __forceinline__ unsigned char f2fp8(float v) {
    return (unsigned char)(__builtin_amdgcn_cvt_pk_fp8_f32(v, 0.f, 0, false) & 0xff);
}
__device__ __forceinline__ unsigned pk4fp8(float a, float b, float c, float d) {
    int r = __builtin_amdgcn_cvt_pk_fp8_f32(a, b, 0, false);
    r = __builtin_amdgcn_cvt_pk_fp8_f32(c, d, r, true);
    return (unsigned)r;
}
__device__ __forceinline__ i32x8 ld32B(const void* p) {
    const uint4 a = ((const uint4*)p)[0];
    const uint4 b = ((const uint4*)p)[1];
    i32x8 r;
    r[0] = a.x; r[1] = a.y; r[2] = a.z; r[3] = a.w;
    r[4] = b.x; r[5] = b.y; r[6] = b.z; r[7] = b.w;
    return r;
}

// ---------------- combined prep: weights (blocks 0..208) + points (209..464) ----------------
__global__ void prep_all(const float* __restrict__ x, const float* __restrict__ pos,
                         const float* __restrict__ Wq, const float* __restrict__ Wk,
                         const float* __restrict__ Wv, const float* __restrict__ pW1,
                         const float* __restrict__ pb1, const float* __restrict__ pW2,
                         const float* __restrict__ pb2, const float* __restrict__ aW1,
                         const float* __restrict__ ab1, const float* __restrict__ aW2,
                         unsigned short* __restrict__ bextf, unsigned char* __restrict__ aw2f8,
                         unsigned short* __restrict__ pw2f, float* __restrict__ cArr,
                         float* __restrict__ qI, unsigned short* __restrict__ kN,
                         float* __restrict__ vPT, float* __restrict__ aI,
                         unsigned short* __restrict__ aJ)
{
    const int b = blockIdx.x;
    if (b < 209) {
        const int idx = b * 256 + threadIdx.x;
        if (idx < 32768) {
            // B_ext[k][t]: k<64 -> W_pa = pW2@aW1, else aW1   (R2-verified)
            const int k = idx >> 8, t = idx & 255;
            float val;
            if (k < 64) {
                float s = 0.f;
                for (int d = 0; d < 64; ++d) s = fmaf(pW2[k * 64 + d], aW1[d * 256 + t], s);
                val = s;
            } else {
                val = aW1[(k - 64) * 256 + t];
            }
            const int kc = k >> 5, kl = k & 31, qq = kl >> 3, e = kl & 7;
            const int ntg = t >> 4, tl = t & 15;
            bextf[(((size_t)(kc * 16 + ntg) * 64) + (qq * 16 + tl)) * 8 + e] = f2b_rne(val);
        } else if (idx < 49152) {
            // aW2*log2e fp8 frags for mfma_scale 16x16x128: one byte per thread.
            // r = ((kb*4 + w)*64 + lane)*32 + e ; lane = q*16+dl ; kp = kb*128+q*32+e
            // H byte layout perm (same formula as bf16, byte-granular):
            //   t(p) = 64*(p>>6) + 16*(p&3) + ((p>>2)&15)
            const int r = idx - 32768;
            const int e = r & 31, lane = (r >> 5) & 63, wsl = (r >> 11) & 3, kb = r >> 13;
            const int q = lane >> 4, dl = lane & 15;
            const int kp = kb * 128 + q * 32 + e;
            const int t = 64 * (kp >> 6) + 16 * (kp & 3) + ((kp >> 2) & 15);
            const int d = 16 * wsl + dl;
            aw2f8[r] = f2fp8(aW2[t * 64 + d] * 1.4426950408889634f);
        } else if (idx < 53248) {
            // pW2 frags (R2-verified)
            const int r = idx - 49152;
            const int k = r >> 6, d = r & 63;
            const int kc = k >> 5, kl = k & 31, qq = kl >> 3, e = kl & 7;
            const int nt = d >> 4, dl = d & 15;
            pw2f[(((size_t)(kc * 4 + nt) * 64) + (qq * 16 + dl)) * 8 + e] = f2b_rne(pW2[k * 64 + d]);
        } else if (idx < 53504) {
            const int t = idx - 53248;
            float s = ab1[t];
            for (int d = 0; d < 64; ++d) s = fmaf(pb2[d], aW1[d * 256 + t], s);
            cArr[t] = s;
        }
    } else {
        // per-point prep: 4 points per block
        const int t = threadIdx.x, sub = t >> 6, d = t & 63;
        const int i = (b - 209) * 4 + sub;
        __shared__ float xs[4][64];
        xs[sub][d] = x[i * 64 + d];
        __syncthreads();
        float q = 0.f, k = 0.f, v = 0.f;
        for (int e = 0; e < 64; ++e) {
            const float xe = xs[sub][e];
            q = fmaf(xe, Wq[e * 64 + d], q);
            k = fmaf(xe, Wk[e * 64 + d], k);
            v = fmaf(xe, Wv[e * 64 + d], v);
        }
        const float a = pos[i * 2] * pW1[d] + pos[i * 2 + 1] * pW1[64 + d];
        qI[i * 64 + d] = q;
        kN[i * 64 + d] = f2b_rne(-k);
        vPT[d * NPTS + i] = v + pb2[d];
        aI[i * 64 + d] = a + pb1[d];
        aJ[i * 64 + d] = f2b_rne(a);
    }
}

// ---------------- main fused kernel: one block per query i, j-tile 32 ----------------
__global__ __launch_bounds__(256, 2) void ptl_main(
    const float* __restrict__ aI, const float* __restrict__ qI,
    const unsigned short* __restrict__ aJ, const unsigned short* __restrict__ kN,
    const float* __restrict__ vPT,
    const unsigned short* __restrict__ bextf, const unsigned char* __restrict__ aw2f8,
    const unsigned short* __restrict__ pw2f, const float* __restrict__ cArr,
    float* __restrict__ out)
{
    const int i    = blockIdx.x;
    const int tid  = threadIdx.x;
    const int w    = tid >> 6;    // wave: t-slice [64w,64w+64) for G1, d-slice [16w,16w+16) for G2/G3
    const int lane = tid & 63;
    const int m    = lane & 15;
    const int q    = lane >> 4;

    // double-buffered LDS: [buf][sub]  (16 KB + 17 KB = 33 KB)
    __shared__ __align__(16) uint4 AfL[2][2][4][64];
    __shared__ __align__(16) unsigned char Hs[2][2][16 * 272];    // fp8 H, stride 272

    // constant B fragments
    sh8 Bf[16];  // G1: [kc 0..3][nt 0..3]
#pragma unroll
    for (int kc = 0; kc < 4; ++kc)
#pragma unroll
        for (int nt = 0; nt < 4; ++nt)
            Bf[kc * 4 + nt] = *(const sh8*)(bextf + ((size_t)((kc * 16 + 4 * w + nt) * 64 + lane)) * 8);
    i32x8 W2f[2];  // G2 fp8: [kb 0..1], d-slice w (16 regs vs bf16's 32)
#pragma unroll
    for (int kb = 0; kb < 2; ++kb)
        W2f[kb] = ld32B(aw2f8 + ((size_t)((kb * 4 + w) * 64 + lane)) * 32);
    sh8 P2f[2];  // G3: [kc 0..1], d-slice w
#pragma unroll
    for (int kc = 0; kc < 2; ++kc)
        P2f[kc] = *(const sh8*)(pw2f + ((size_t)((kc * 4 + w) * 64 + lane)) * 8);

    float creg[4];
#pragma unroll
    for (int nt = 0; nt < 4; ++nt) creg[nt] = cArr[64 * w + 16 * nt + m];

    // builder: wave w builds A-frag k-block w (w<2: relu1 halves, w>=2: q-k halves)
    const int  half   = w & 1;
    const bool isRelu = (w < 2);
    const unsigned short* bsrc  = (isRelu ? aJ : kN) + m * 64 + half * 32 + q * 8;
    const float*          ibase = (isRelu ? aI : qI) + i * 64 + half * 32 + q * 8;
    float iv[8];
    *(float4*)(iv)     = *(const float4*)(ibase);
    *(float4*)(iv + 4) = *(const float4*)(ibase + 4);

    // prologue: build both subs of tile 0 into buffer 0
#pragma unroll
    for (int s = 0; s < 2; ++s) {
        const sh8 raw = *(const sh8*)(bsrc + (size_t)(16 * s) * 64);
        float t[8];
#pragma unroll
        for (int e = 0; e < 8; ++e)
            t[e] = isRelu ? fmaxf(iv[e] - b2f((unsigned short)raw[e]), 0.f)
                          : iv[e] + b2f((unsigned short)raw[e]);
        uint4 pk;
        pk.x = pk2(t[0], t[1]); pk.y = pk2(t[2], t[3]);
        pk.z = pk2(t[4], t[5]); pk.w = pk2(t[6], t[7]);
        AfL[0][s][w][lane] = pk;
    }
    __syncthreads();

    float num = 0.f, den = 0.f;
    const f32x4 z4 = {0.f, 0.f, 0.f, 0.f};
    const float* vbase = vPT + (size_t)(16 * w + m) * NPTS;

    for (int n = 0; n < 32; ++n) {
        const int pb = n & 1, nb = pb ^ 1;
        const int j0 = n << 5;

        // next tile's raw global loads, issued early (hidden under G1)
        sh8 raw0, raw1;
        if (n < 31) {
            raw0 = *(const sh8*)(bsrc + (size_t)(j0 + 32) * 64);
            raw1 = *(const sh8*)(bsrc + (size_t)(j0 + 48) * 64);
        }
        // v values for own tile (C-operand of G3)
        const float4 vj0 = *(const float4*)(vbase + j0 + 4 * q);
        const float4 vj1 = *(const float4*)(vbase + j0 + 16 + 4 * q);

        // ---- sub 0: G1 + H-write (fp8 pack) ----
        const sh8 A00 = *(const sh8*)&AfL[pb][0][0][lane];  // relu1 (live for G3)
        const sh8 A01 = *(const sh8*)&AfL[pb][0][1][lane];
        const sh8 A02 = *(const sh8*)&AfL[pb][0][2][lane];
        const sh8 A03 = *(const sh8*)&AfL[pb][0][3][lane];
        {
            f32x4 acc[4];
#pragma unroll
            for (int nt = 0; nt < 4; ++nt) {
                const f32x4 cv = {creg[nt], creg[nt], creg[nt], creg[nt]};
                acc[nt] = __builtin_amdgcn_mfma_f32_16x16x32_bf16(A00, Bf[0 * 4 + nt], cv, 0, 0, 0);
                acc[nt] = __builtin_amdgcn_mfma_f32_16x16x32_bf16(A01, Bf[1 * 4 + nt], acc[nt], 0, 0, 0);
                acc[nt] = __builtin_amdgcn_mfma_f32_16x16x32_bf16(A02, Bf[2 * 4 + nt], acc[nt], 0, 0, 0);
                acc[nt] = __builtin_amdgcn_mfma_f32_16x16x32_bf16(A03, Bf[3 * 4 + nt], acc[nt], 0, 0, 0);
            }
            // byte col p = 64w + 4m + nt ; perm t(p) = 64w + 16nt + m matches acc[nt] col
            unsigned char* hw = Hs[pb][0] + (4 * q) * 272 + 64 * w + 4 * m;
#pragma unroll
            for (int r = 0; r < 4; ++r)
                *(unsigned*)(hw + r * 272) = pk4fp8(fmaxf(acc[0][r], 0.f), fmaxf(acc[1][r], 0.f),
                                                   fmaxf(acc[2][r], 0.f), fmaxf(acc[3][r], 0.f));
        }

        // ---- sub 1: G1 + H-write ----
        const sh8 A10 = *(const sh8*)&AfL[pb][1][0][lane];  // relu1 (live for G3)
        const sh8 A11 = *(const sh8*)&AfL[pb][1][1][lane];
        const sh8 A12 = *(const sh8*)&AfL[pb][1][2][lane];
        const sh8 A13 = *(const sh8*)&AfL[pb][1][3][lane];
        {
            f32x4 acc[4];
#pragma unroll
            for (int nt = 0; nt < 4; ++nt) {
                const f32x4 cv = {creg[nt], creg[nt], creg[nt], creg[nt]};
                acc[nt] = __builtin_amdgcn_mfma_f32_16x16x32_bf16(A10, Bf[0 * 4 + nt], cv, 0, 0, 0);
                acc[nt] = __builtin_amdgcn_mfma_f32_16x16x32_bf16(A11, Bf[1 * 4 + nt], acc[nt], 0, 0, 0);
                acc[nt] = __builtin_amdgcn_mfma_f32_16x16x32_bf16(A12, Bf[2 * 4 + nt], acc[nt], 0, 0, 0);
                acc[nt] = __builtin_amdgcn_mfma_f32_16x16x32_bf16(A13, Bf[3 * 4 + nt], acc[nt], 0, 0, 0);
            }
            unsigned char* hw = Hs[pb][1] + (4 * q) * 272 + 64 * w + 4 * m;
#pragma unroll
            for (int r = 0; r < 4; ++r)
                *(unsigned*)(hw + r * 272) = pk4fp8(fmaxf(acc[0][r], 0.f), fmaxf(acc[1][r], 0.f),
                                                   fmaxf(acc[2][r], 0.f), fmaxf(acc[3][r], 0.f));
        }

        // build next tile's A-frags (this wave's k-block, both subs)
        if (n < 31) {
#pragma unroll
            for (int s = 0; s < 2; ++s) {
                const sh8 raw = s ? raw1 : raw0;
                float t[8];
#pragma unroll
                for (int e = 0; e < 8; ++e)
                    t[e] = isRelu ? fmaxf(iv[e] - b2f((unsigned short)raw[e]), 0.f)
                                  : iv[e] + b2f((unsigned short)raw[e]);
                uint4 pk;
                pk.x = pk2(t[0], t[1]); pk.y = pk2(t[2], t[3]);
                pk.z = pk2(t[4], t[5]); pk.w = pk2(t[6], t[7]);
                AfL[nb][s][w][lane] = pk;
            }
        }

        __syncthreads();  // the ONE barrier per 32 j: publishes Hs[pb][*] and AfL[nb][*]

        // ---- G2: simL2, fp8 K=256 = two 16x16x128 per sub (unit scales) ----
        f32x4 aS0 = z4, aS1 = z4;
#pragma unroll
        for (int kb = 0; kb < 2; ++kb) {
            const i32x8 h0 = ld32B(Hs[pb][0] + m * 272 + kb * 128 + 32 * q);
            aS0 = __builtin_amdgcn_mfma_scale_f32_16x16x128_f8f6f4(
                h0, W2f[kb], aS0, 0, 0, 0, 127, 0, 127);
            const i32x8 h1 = ld32B(Hs[pb][1] + m * 272 + kb * 128 + 32 * q);
            aS1 = __builtin_amdgcn_mfma_scale_f32_16x16x128_f8f6f4(
                h1, W2f[kb], aS1, 0, 0, 0, 127, 0, 127);
        }
        // ---- G3: rpe + v (C-op), relu1 A-frags from registers ----
        const f32x4 vc0 = {vj0.x, vj0.y, vj0.z, vj0.w};
        const f32x4 vc1 = {vj1.x, vj1.y, vj1.z, vj1.w};
        f32x4 aR0 = __builtin_amdgcn_mfma_f32_16x16x32_bf16(A00, P2f[0], vc0, 0, 0, 0);
        aR0 = __builtin_amdgcn_mfma_f32_16x16x32_bf16(A01, P2f[1], aR0, 0, 0, 0);
        f32x4 aR1 = __builtin_amdgcn_mfma_f32_16x16x32_bf16(A10, P2f[0], vc1, 0, 0, 0);
        aR1 = __builtin_amdgcn_mfma_f32_16x16x32_bf16(A11, P2f[1], aR1, 0, 0, 0);

        // online accumulation
#pragma unroll
        for (int r = 0; r < 4; ++r) {
            const float e0 = exp2f(aS0[r]);
            num = fmaf(e0, aR0[r], num);
            den += e0;
            const float e1 = exp2f(aS1[r]);
            num = fmaf(e1, aR1[r], num);
            den += e1;
        }
    }

    // reduce the 4 quad-partials (lanes m, m+16, m+32, m+48)
    num += __shfl_xor(num, 16);
    num += __shfl_xor(num, 32);
    den += __shfl_xor(den, 16);
    den += __shfl_xor(den, 32);
    if (q == 0) out[i * 64 + 16 * w + m] = num / den;
}

extern "C" void kernel_launch(void* const* d_in, const int* in_sizes, int n_in,
                              void* d_out, int out_size, void* d_ws, size_t ws_size,
                              hipStream_t stream) {
    const float* x   = (const float*)d_in[0];
    const float* pos = (const float*)d_in[1];
    const float* Wq  = (const float*)d_in[2];
    const float* Wk  = (const float*)d_in[3];
    const float* Wv  = (const float*)d_in[4];
    const float* pW1 = (const float*)d_in[5];
    const float* pb1 = (const float*)d_in[6];
    const float* pW2 = (const float*)d_in[7];
    const float* pb2 = (const float*)d_in[8];
    const float* aW1 = (const float*)d_in[9];
    const float* ab1 = (const float*)d_in[10];
    const float* aW2 = (const float*)d_in[11];
    // d_in[12] = ab2: constant over j -> cancels in per-channel softmax, unused.

    char* ws = (char*)d_ws;
    unsigned short* bextf = (unsigned short*)(ws + BEXT_OFF);
    unsigned char*  aw2f8 = (unsigned char*)(ws + AW2F_OFF);
    unsigned short* pw2f  = (unsigned short*)(ws + PW2F_OFF);
    float*          cArr  = (float*)(ws + CARR_OFF);
    float*          aIa   = (float*)(ws + AI_OFF);
    float*          qIa   = (float*)(ws + QI_OFF);
    float*          vPTa  = (float*)(ws + VPT_OFF);
    unsigned short* aJa   = (unsigned short*)(ws + AJ_OFF);
    unsigned short* kNa   = (unsigned short*)(ws + KN_OFF);

    prep_all<<<465, 256, 0, stream>>>(x, pos, Wq, Wk, Wv, pW1, pb1, pW2, pb2, aW1, ab1, aW2,
                                      bextf, aw2f8, pw2f, cArr, qIa, kNa, vPTa, aIa, aJa);
    ptl_main<<<NPTS, 256, 0, stream>>>(aIa, qIa, aJa, kNa, vPTa, bextf, aw2f8, pw2f, cArr,
                                       (float*)d_out);
}

// Round 10
// 181.577 us; speedup vs baseline: 1.9738x; 1.0448x over previous
//
#include <hip/hip_runtime.h>

// PointTransformerLayer fused kernel (MI355X / gfx950) — round 10
//
// Math (bf16 G1/G3 verified R2/R4 absmax 0.031; fp8 H/G2 verified R9 0.0625):
//   relu1 = relu(aI_i - a_j)            aI = pos@pW1 + pb1, a = pos@pW1
//   S1    = [relu1 | (q_i - k_j)] @ [[W_pa],[aW1]]   (K=128), W_pa = pW2@aW1
//   H     = relu(S1 + c), c = ab1 + pb2@aW1          (c folded into G1 C-op)
//   simL2 = H @ (aW2*log2e)              (ab2 softmax-invariant -> dropped)
//   rpe   = relu1 @ pW2 ; vv = (v+pb2)_j + rpe       (v folded into G3 C-op)
//   out_i[d] = sum_j 2^simL2 * vv / sum_j 2^simL2
//
// R10 = R9 (189.7us best: fp8 H/G2, j-tile 32, 1 barrier/iter) + two fixes:
//   1. G3 HOISTED PRE-BARRIER (it never depended on the barrier!) — carries
//      aR (8 f32) across the barrier instead of 4 A-frags (32 regs); shortens
//      the post-barrier critical path to ld32B->G2->softmax only. Math is
//      bit-identical (same MFMAs, same order, earlier schedule).
//   2. exp2 via raw v_exp_f32 (__builtin_amdgcn_exp2f, guarded) — simL2 is
//      bounded, libm range handling is dead weight.
// R6/R7 measured +24 live regs = +11us at 2 waves/SIMD; this is -24.

typedef float f32x4 __attribute__((ext_vector_type(4)));
typedef int   i32x8 __attribute__((ext_vector_type(8)));
using sh8 = __attribute__((ext_vector_type(8))) short;  // 8 bf16 (4 VGPRs)

static constexpr int NPTS = 1024;

#if __has_builtin(__builtin_amdgcn_exp2f)
#define EXP2(x) __builtin_amdgcn_exp2f(x)
#else
#define EXP2(x) exp2f(x)
#endif

// ---- ws layout (bytes) — identical to R9 ----
static constexpr size_t BEXT_OFF = 0;        // 4*16*64*8 bf16  = 65536 B
static constexpr size_t AW2F_OFF = 65536;    // fp8 frags: 2*4*64*32 = 16384 B
static constexpr size_t PW2F_OFF = 98304;    // 2*4*64*8 bf16   = 8192 B
static constexpr size_t CARR_OFF = 106496;   // 256 f32         = 1024 B
static constexpr size_t AI_OFF   = 107520;   // 1024*64 f32 (+pb1)
static constexpr size_t QI_OFF   = 369664;   // 1024*64 f32
static constexpr size_t VPT_OFF  = 631808;   // 64*1024 f32 (v+pb2, transposed)
static constexpr size_t AJ_OFF   = 893952;   // 1024*64 bf16
static constexpr size_t KN_OFF   = 1025024;  // 1024*64 bf16 (negated k)

__device__ __forceinline__ unsigned short f2b_rne(float f) {
    unsigned u = __float_as_uint(f);
    u += 0x7fffu + ((u >> 16) & 1u);
    return (unsigned short)(u >> 16);
}
// trunc-pack two f32 into bf16x2 — single v_perm_b32
__device__ __forceinline__ unsigned pk2(float lo, float hi) {
    return __builtin_amdgcn_perm(__float_as_uint(hi), __float_as_uint(lo), 0x07060302);
}
__device__ __forceinline__ float b2f(unsigned short s) {
    return __uint_as_float(((unsigned)s) << 16);
}
__device__ __forceinline__ unsigned char f2fp8(float v) {
    return (unsigned char)(__builtin_amdgcn_cvt_pk_fp8_f32(v, 0.f, 0, false) & 0xff);
}
__device__ __forceinline__ unsigned pk4fp8(float a, float b, float c, float d) {
    int r = __builtin_amdgcn_cvt_pk_fp8_f32(a, b, 0, false);
    r = __builtin_amdgcn_cvt_pk_fp8_f32(c, d, r, true);
    return (unsigned)r;
}
__device__ __forceinline__ i32x8 ld32B(const void* p) {
    const uint4 a = ((const uint4*)p)[0];
    const uint4 b = ((const uint4*)p)[1];
    i32x8 r;
    r[0] = a.x; r[1] = a.y; r[2] = a.z; r[3] = a.w;
    r[4] = b.x; r[5] = b.y; r[6] = b.z; r[7] = b.w;
    return r;
}

// ---------------- combined prep: weights (blocks 0..208) + points (209..464) ----------------
__global__ void prep_all(const float* __restrict__ x, const float* __restrict__ pos,
                         const float* __restrict__ Wq, const float* __restrict__ Wk,
                         const float* __restrict__ Wv, const float* __restrict__ pW1,
                         const float* __restrict__ pb1, const float* __restrict__ pW2,
                         const float* __restrict__ pb2, const float* __restrict__ aW1,
                         const float* __restrict__ ab1, const float* __restrict__ aW2,
                         unsigned short* __restrict__ bextf, unsigned char* __restrict__ aw2f8,
                         unsigned short* __restrict__ pw2f, float* __restrict__ cArr,
                         float* __restrict__ qI, unsigned short* __restrict__ kN,
                         float* __restrict__ vPT, float* __restrict__ aI,
                         unsigned short* __restrict__ aJ)
{
    const int b = blockIdx.x;
    if (b < 209) {
        const int idx = b * 256 + threadIdx.x;
        if (idx < 32768) {
            // B_ext[k][t]: k<64 -> W_pa = pW2@aW1, else aW1   (R2-verified)
            const int k = idx >> 8, t = idx & 255;
            float val;
            if (k < 64) {
                float s = 0.f;
                for (int d = 0; d < 64; ++d) s = fmaf(pW2[k * 64 + d], aW1[d * 256 + t], s);
                val = s;
            } else {
                val = aW1[(k - 64) * 256 + t];
            }
            const int kc = k >> 5, kl = k & 31, qq = kl >> 3, e = kl & 7;
            const int ntg = t >> 4, tl = t & 15;
            bextf[(((size_t)(kc * 16 + ntg) * 64) + (qq * 16 + tl)) * 8 + e] = f2b_rne(val);
        } else if (idx < 49152) {
            // aW2*log2e fp8 frags for mfma_scale 16x16x128 (R9-verified)
            const int r = idx - 32768;
            const int e = r & 31, lane = (r >> 5) & 63, wsl = (r >> 11) & 3, kb = r >> 13;
            const int q = lane >> 4, dl = lane & 15;
            const int kp = kb * 128 + q * 32 + e;
            const int t = 64 * (kp >> 6) + 16 * (kp & 3) + ((kp >> 2) & 15);
            const int d = 16 * wsl + dl;
            aw2f8[r] = f2fp8(aW2[t * 64 + d] * 1.4426950408889634f);
        } else if (idx < 53248) {
            // pW2 frags (R2-verified)
            const int r = idx - 49152;
            const int k = r >> 6, d = r & 63;
            const int kc = k >> 5, kl = k & 31, qq = kl >> 3, e = kl & 7;
            const int nt = d >> 4, dl = d & 15;
            pw2f[(((size_t)(kc * 4 + nt) * 64) + (qq * 16 + dl)) * 8 + e] = f2b_rne(pW2[k * 64 + d]);
        } else if (idx < 53504) {
            const int t = idx - 53248;
            float s = ab1[t];
            for (int d = 0; d < 64; ++d) s = fmaf(pb2[d], aW1[d * 256 + t], s);
            cArr[t] = s;
        }
    } else {
        // per-point prep: 4 points per block
        const int t = threadIdx.x, sub = t >> 6, d = t & 63;
        const int i = (b - 209) * 4 + sub;
        __shared__ float xs[4][64];
        xs[sub][d] = x[i * 64 + d];
        __syncthreads();
        float q = 0.f, k = 0.f, v = 0.f;
        for (int e = 0; e < 64; ++e) {
            const float xe = xs[sub][e];
            q = fmaf(xe, Wq[e * 64 + d], q);
            k = fmaf(xe, Wk[e * 64 + d], k);
            v = fmaf(xe, Wv[e * 64 + d], v);
        }
        const float a = pos[i * 2] * pW1[d] + pos[i * 2 + 1] * pW1[64 + d];
        qI[i * 64 + d] = q;
        kN[i * 64 + d] = f2b_rne(-k);
        vPT[d * NPTS + i] = v + pb2[d];
        aI[i * 64 + d] = a + pb1[d];
        aJ[i * 64 + d] = f2b_rne(a);
    }
}

// ---------------- main fused kernel: one block per query i, j-tile 32 ----------------
__global__ __launch_bounds__(256, 2) void ptl_main(
    const float* __restrict__ aI, const float* __restrict__ qI,
    const unsigned short* __restrict__ aJ, const unsigned short* __restrict__ kN,
    const float* __restrict__ vPT,
    const unsigned short* __restrict__ bextf, const unsigned char* __restrict__ aw2f8,
    const unsigned short* __restrict__ pw2f, const float* __restrict__ cArr,
    float* __restrict__ out)
{
    const int i    = blockIdx.x;
    const int tid  = threadIdx.x;
    const int w    = tid >> 6;    // wave: t-slice [64w,64w+64) for G1, d-slice [16w,16w+16) for G2/G3
    const int lane = tid & 63;
    const int m    = lane & 15;
    const int q    = lane >> 4;

    // double-buffered LDS: [buf][sub]  (16 KB + 17 KB = 33 KB)
    __shared__ __align__(16) uint4 AfL[2][2][4][64];
    __shared__ __align__(16) unsigned char Hs[2][2][16 * 272];    // fp8 H, stride 272

    // constant B fragments
    sh8 Bf[16];  // G1: [kc 0..3][nt 0..3]
#pragma unroll
    for (int kc = 0; kc < 4; ++kc)
#pragma unroll
        for (int nt = 0; nt < 4; ++nt)
            Bf[kc * 4 + nt] = *(const sh8*)(bextf + ((size_t)((kc * 16 + 4 * w + nt) * 64 + lane)) * 8);
    i32x8 W2f[2];  // G2 fp8: [kb 0..1], d-slice w
#pragma unroll
    for (int kb = 0; kb < 2; ++kb)
        W2f[kb] = ld32B(aw2f8 + ((size_t)((kb * 4 + w) * 64 + lane)) * 32);
    sh8 P2f[2];  // G3: [kc 0..1], d-slice w
#pragma unroll
    for (int kc = 0; kc < 2; ++kc)
        P2f[kc] = *(const sh8*)(pw2f + ((size_t)((kc * 4 + w) * 64 + lane)) * 8);

    float creg[4];
#pragma unroll
    for (int nt = 0; nt < 4; ++nt) creg[nt] = cArr[64 * w + 16 * nt + m];

    // builder: wave w builds A-frag k-block w (w<2: relu1 halves, w>=2: q-k halves)
    const int  half   = w & 1;
    const bool isRelu = (w < 2);
    const unsigned short* bsrc  = (isRelu ? aJ : kN) + m * 64 + half * 32 + q * 8;
    const float*          ibase = (isRelu ? aI : qI) + i * 64 + half * 32 + q * 8;
    float iv[8];
    *(float4*)(iv)     = *(const float4*)(ibase);
    *(float4*)(iv + 4) = *(const float4*)(ibase + 4);

    // prologue: build both subs of tile 0 into buffer 0
#pragma unroll
    for (int s = 0; s < 2; ++s) {
        const sh8 raw = *(const sh8*)(bsrc + (size_t)(16 * s) * 64);
        float t[8];
#pragma unroll
        for (int e = 0; e < 8; ++e)
            t[e] = isRelu ? fmaxf(iv[e] - b2f((unsigned short)raw[e]), 0.f)
                          : iv[e] + b2f((unsigned short)raw[e]);
        uint4 pk;
        pk.x = pk2(t[0], t[1]); pk.y = pk2(t[2], t[3]);
        pk.z = pk2(t[4], t[5]); pk.w = pk2(t[6], t[7]);
        AfL[0][s][w][lane] = pk;
    }
    __syncthreads();

    float num = 0.f, den = 0.f;
    const f32x4 z4 = {0.f, 0.f, 0.f, 0.f};
    const float* vbase = vPT + (size_t)(16 * w + m) * NPTS;

    for (int n = 0; n < 32; ++n) {
        const int pb = n & 1, nb = pb ^ 1;
        const int j0 = n << 5;

        // next tile's raw global loads, issued early (hidden under G1)
        sh8 raw0, raw1;
        if (n < 31) {
            raw0 = *(const sh8*)(bsrc + (size_t)(j0 + 32) * 64);
            raw1 = *(const sh8*)(bsrc + (size_t)(j0 + 48) * 64);
        }
        // v values for own tile (C-operand of G3)
        const float4 vj0 = *(const float4*)(vbase + j0 + 4 * q);
        const float4 vj1 = *(const float4*)(vbase + j0 + 16 + 4 * q);

        // ---- sub 0: G1 + H-write (fp8 pack) ----
        const sh8 A00 = *(const sh8*)&AfL[pb][0][0][lane];  // relu1
        const sh8 A01 = *(const sh8*)&AfL[pb][0][1][lane];
        const sh8 A02 = *(const sh8*)&AfL[pb][0][2][lane];
        const sh8 A03 = *(const sh8*)&AfL[pb][0][3][lane];
        {
            f32x4 acc[4];
#pragma unroll
            for (int nt = 0; nt < 4; ++nt) {
                const f32x4 cv = {creg[nt], creg[nt], creg[nt], creg[nt]};
                acc[nt] = __builtin_amdgcn_mfma_f32_16x16x32_bf16(A00, Bf[0 * 4 + nt], cv, 0, 0, 0);
                acc[nt] = __builtin_amdgcn_mfma_f32_16x16x32_bf16(A01, Bf[1 * 4 + nt], acc[nt], 0, 0, 0);
                acc[nt] = __builtin_amdgcn_mfma_f32_16x16x32_bf16(A02, Bf[2 * 4 + nt], acc[nt], 0, 0, 0);
                acc[nt] = __builtin_amdgcn_mfma_f32_16x16x32_bf16(A03, Bf[3 * 4 + nt], acc[nt], 0, 0, 0);
            }
            unsigned char* hw = Hs[pb][0] + (4 * q) * 272 + 64 * w + 4 * m;
#pragma unroll
            for (int r = 0; r < 4; ++r)
                *(unsigned*)(hw + r * 272) = pk4fp8(fmaxf(acc[0][r], 0.f), fmaxf(acc[1][r], 0.f),
                                                   fmaxf(acc[2][r], 0.f), fmaxf(acc[3][r], 0.f));
        }

        // ---- sub 1: G1 + H-write ----
        const sh8 A10 = *(const sh8*)&AfL[pb][1][0][lane];  // relu1
        const sh8 A11 = *(const sh8*)&AfL[pb][1][1][lane];
        const sh8 A12 = *(const sh8*)&AfL[pb][1][2][lane];
        const sh8 A13 = *(const sh8*)&AfL[pb][1][3][lane];
        {
            f32x4 acc[4];
#pragma unroll
            for (int nt = 0; nt < 4; ++nt) {
                const f32x4 cv = {creg[nt], creg[nt], creg[nt], creg[nt]};
                acc[nt] = __builtin_amdgcn_mfma_f32_16x16x32_bf16(A10, Bf[0 * 4 + nt], cv, 0, 0, 0);
                acc[nt] = __builtin_amdgcn_mfma_f32_16x16x32_bf16(A11, Bf[1 * 4 + nt], acc[nt], 0, 0, 0);
                acc[nt] = __builtin_amdgcn_mfma_f32_16x16x32_bf16(A12, Bf[2 * 4 + nt], acc[nt], 0, 0, 0);
                acc[nt] = __builtin_amdgcn_mfma_f32_16x16x32_bf16(A13, Bf[3 * 4 + nt], acc[nt], 0, 0, 0);
            }
            unsigned char* hw = Hs[pb][1] + (4 * q) * 272 + 64 * w + 4 * m;
#pragma unroll
            for (int r = 0; r < 4; ++r)
                *(unsigned*)(hw + r * 272) = pk4fp8(fmaxf(acc[0][r], 0.f), fmaxf(acc[1][r], 0.f),
                                                   fmaxf(acc[2][r], 0.f), fmaxf(acc[3][r], 0.f));
        }

        // ---- G3 PRE-BARRIER (no barrier dependency): rpe + v, aR carried ----
        const f32x4 vc0 = {vj0.x, vj0.y, vj0.z, vj0.w};
        const f32x4 vc1 = {vj1.x, vj1.y, vj1.z, vj1.w};
        f32x4 aR0 = __builtin_amdgcn_mfma_f32_16x16x32_bf16(A00, P2f[0], vc0, 0, 0, 0);
        aR0 = __builtin_amdgcn_mfma_f32_16x16x32_bf16(A01, P2f[1], aR0, 0, 0, 0);
        f32x4 aR1 = __builtin_amdgcn_mfma_f32_16x16x32_bf16(A10, P2f[0], vc1, 0, 0, 0);
        aR1 = __builtin_amdgcn_mfma_f32_16x16x32_bf16(A11, P2f[1], aR1, 0, 0, 0);

        // build next tile's A-frags (this wave's k-block, both subs)
        if (n < 31) {
#pragma unroll
            for (int s = 0; s < 2; ++s) {
                const sh8 raw = s ? raw1 : raw0;
                float t[8];
#pragma unroll
                for (int e = 0; e < 8; ++e)
                    t[e] = isRelu ? fmaxf(iv[e] - b2f((unsigned short)raw[e]), 0.f)
                                  : iv[e] + b2f((unsigned short)raw[e]);
                uint4 pk;
                pk.x = pk2(t[0], t[1]); pk.y = pk2(t[2], t[3]);
                pk.z = pk2(t[4], t[5]); pk.w = pk2(t[6], t[7]);
                AfL[nb][s][w][lane] = pk;
            }
        }

        __syncthreads();  // the ONE barrier per 32 j: publishes Hs[pb][*] and AfL[nb][*]

        // ---- G2: simL2, fp8 K=256 = two 16x16x128 per sub (unit scales) ----
        f32x4 aS0 = z4, aS1 = z4;
#pragma unroll
        for (int kb = 0; kb < 2; ++kb) {
            const i32x8 h0 = ld32B(Hs[pb][0] + m * 272 + kb * 128 + 32 * q);
            aS0 = __builtin_amdgcn_mfma_scale_f32_16x16x128_f8f6f4(
                h0, W2f[kb], aS0, 0, 0, 0, 127, 0, 127);
            const i32x8 h1 = ld32B(Hs[pb][1] + m * 272 + kb * 128 + 32 * q);
            aS1 = __builtin_amdgcn_mfma_scale_f32_16x16x128_f8f6f4(
                h1, W2f[kb], aS1, 0, 0, 0, 127, 0, 127);
        }

        // online accumulation (aR0/aR1 carried from pre-barrier)
#pragma unroll
        for (int r = 0; r < 4; ++r) {
            const float e0 = EXP2(aS0[r]);
            num = fmaf(e0, aR0[r], num);
            den += e0;
            const float e1 = EXP2(aS1[r]);
            num = fmaf(e1, aR1[r], num);
            den += e1;
        }
    }

    // reduce the 4 quad-partials (lanes m, m+16, m+32, m+48)
    num += __shfl_xor(num, 16);
    num += __shfl_xor(num, 32);
    den += __shfl_xor(den, 16);
    den += __shfl_xor(den, 32);
    if (q == 0) out[i * 64 + 16 * w + m] = num / den;
}

extern "C" void kernel_launch(void* const* d_in, const int* in_sizes, int n_in,
                              void* d_out, int out_size, void* d_ws, size_t ws_size,
                              hipStream_t stream) {
    const float* x   = (const float*)d_in[0];
    const float* pos = (const float*)d_in[1];
    const float* Wq  = (const float*)d_in[2];
    const float* Wk  = (const float*)d_in[3];
    const float* Wv  = (const float*)d_in[4];
    const float* pW1 = (const float*)d_in[5];
    const float* pb1 = (const float*)d_in[6];
    const float* pW2 = (const float*)d_in[7];
    const float* pb2 = (const float*)d_in[8];
    const float* aW1 = (const float*)d_in[9];
    const float* ab1 = (const float*)d_in[10];
    const float* aW2 = (const float*)d_in[11];
    // d_in[12] = ab2: constant over j -> cancels in per-channel softmax, unused.

    char* ws = (char*)d_ws;
    unsigned short* bextf = (unsigned short*)(ws + BEXT_OFF);
    unsigned char*  aw2f8 = (unsigned char*)(ws + AW2F_OFF);
    unsigned short* pw2f  = (unsigned short*)(ws + PW2F_OFF);
    float*          cArr  = (float*)(ws + CARR_OFF);
    float*          aIa   = (float*)(ws + AI_OFF);
    float*          qIa   = (float*)(ws + QI_OFF);
    float*          vPTa  = (float*)(ws + VPT_OFF);
    unsigned short* aJa   = (unsigned short*)(ws + AJ_OFF);
    unsigned short* kNa   = (unsigned short*)(ws + KN_OFF);

    prep_all<<<465, 256, 0, stream>>>(x, pos, Wq, Wk, Wv, pW1, pb1, pW2, pb2, aW1, ab1, aW2,
                                      bextf, aw2f8, pw2f, cArr, qIa, kNa, vPTa, aIa, aJa);
    ptl_main<<<NPTS, 256, 0, stream>>>(aIa, qIa, aJa, kNa, vPTa, bextf, aw2f8, pw2f, cArr,
                                       (float*)d_out);
}